// Round 2
// baseline (503.104 us; speedup 1.0000x reference)
//
#include <hip/hip_runtime.h>

#define D_INX 128
#define D_HX  128
#define FOURH 512
#define KTOT  256   // K = D_IN + D_H

typedef __attribute__((ext_vector_type(8))) short bf16x8;
typedef __attribute__((ext_vector_type(4))) float f32x4;
typedef __attribute__((ext_vector_type(4))) int   i32x4;

__device__ inline unsigned rnd_bf16(float f){
  unsigned u = __builtin_bit_cast(unsigned, f);
  u += 0x7fffu + ((u >> 16) & 1u);   // RNE
  return u;
}
__device__ inline int pk2(float a, float b){
  unsigned ua = rnd_bf16(a), ub = rnd_bf16(b);
  return (int)((ua >> 16) | (ub & 0xffff0000u));
}
__device__ inline float fsigmoid(float v){
  float e = __builtin_amdgcn_exp2f(v * -1.442695040888963f);
  return __builtin_amdgcn_rcpf(1.0f + e);
}
__device__ inline float ftanhf(float v){
  float e = __builtin_amdgcn_exp2f(v * 2.885390081777927f); // e^{2v}
  return 1.0f - 2.0f * __builtin_amdgcn_rcpf(1.0f + e);
}

// Build Wt[n=4H][k=256] bf16 (transposed, gate-concat) + bcat[512] fp32 in ws.
__global__ void prep_weights(const float* __restrict__ Wxi, const float* __restrict__ Whi, const float* __restrict__ bi,
                             const float* __restrict__ Wxf, const float* __restrict__ Whf, const float* __restrict__ bf_,
                             const float* __restrict__ Wxc, const float* __restrict__ Whc, const float* __restrict__ bc,
                             const float* __restrict__ Wxo, const float* __restrict__ Who, const float* __restrict__ bo,
                             unsigned short* __restrict__ Wt, float* __restrict__ bcat){
  int n = blockIdx.x;        // 0..511  (gate*128 + h)
  int k = threadIdx.x;       // 0..255  (x-part then h-part)
  int g = n >> 7, hc = n & 127;
  const float* Wx = (g == 0) ? Wxi : (g == 1) ? Wxf : (g == 2) ? Wxc : Wxo;
  const float* Wh = (g == 0) ? Whi : (g == 1) ? Whf : (g == 2) ? Whc : Who;
  float v = (k < 128) ? Wx[k * D_HX + hc] : Wh[(k - 128) * D_HX + hc];
  Wt[n * KTOT + k] = (unsigned short)(rnd_bf16(v) >> 16);
  if (k == 0){
    const float* bp = (g == 0) ? bi : (g == 1) ? bf_ : (g == 2) ? bc : bo;
    bcat[n] = bp[hc];
  }
}

// Block: 512 thr = 8 waves (wave = 64 lanes on CDNA!).
// Waves 0-3: rows [0,32) of block; waves 4-7: rows [32,64).
// Wave (wid&3) owns h-cols [(wid&3)*32, +32) for ALL 4 gates -> elementwise is lane-local.
__global__ __launch_bounds__(512, 4)
void lstm_fused(const float* __restrict__ x, const float* __restrict__ hin,
                const float* __restrict__ cin, const unsigned short* __restrict__ Wt,
                const float* __restrict__ bcat, float* __restrict__ out, int Btot){
  const int tid  = threadIdx.x;
  const int l    = tid & 63;
  const int wid  = tid >> 6;       // 0..7
  const int mgrp = wid >> 2;       // 0/1
  const int hs   = wid & 3;        // h-slice
  const int rowbase = blockIdx.x * 64 + mgrp * 32;
  const int hbase   = hs * 32;
  const int l15   = l & 15;
  const int lg    = l >> 4;        // 0..3
  const int klane = lg * 8;

  f32x4 acc[2][4][2];
  #pragma unroll
  for (int m = 0; m < 2; ++m)
    #pragma unroll
    for (int g = 0; g < 4; ++g)
      #pragma unroll
      for (int t = 0; t < 2; ++t)
        acc[m][g][t] = (f32x4){0.f, 0.f, 0.f, 0.f};

  #pragma unroll
  for (int ks = 0; ks < 8; ++ks){
    const float* s = (ks < 4) ? x : hin;
    const int koff = (ks & 3) * 32 + klane;
    bf16x8 a[2];
    #pragma unroll
    for (int m = 0; m < 2; ++m){
      const float* p = s + (size_t)(rowbase + m * 16 + l15) * D_INX + koff;
      float4 f0 = *(const float4*)(p);
      float4 f1 = *(const float4*)(p + 4);
      i32x4 pk;
      pk[0] = pk2(f0.x, f0.y); pk[1] = pk2(f0.z, f0.w);
      pk[2] = pk2(f1.x, f1.y); pk[3] = pk2(f1.z, f1.w);
      a[m] = __builtin_bit_cast(bf16x8, pk);
    }
    #pragma unroll
    for (int g = 0; g < 4; ++g){
      #pragma unroll
      for (int t = 0; t < 2; ++t){
        const int ncol = g * 128 + hbase + t * 16 + l15;
        bf16x8 bw = *(const bf16x8*)(Wt + (size_t)ncol * KTOT + ks * 32 + klane);
        acc[0][g][t] = __builtin_amdgcn_mfma_f32_16x16x32_bf16(a[0], bw, acc[0][g][t], 0, 0, 0);
        acc[1][g][t] = __builtin_amdgcn_mfma_f32_16x16x32_bf16(a[1], bw, acc[1][g][t], 0, 0, 0);
      }
    }
  }

  // Bias per (gate, tile) — col depends only on lane.
  float bb[4][2];
  #pragma unroll
  for (int g = 0; g < 4; ++g)
    #pragma unroll
    for (int t = 0; t < 2; ++t)
      bb[g][t] = bcat[g * 128 + hbase + t * 16 + l15];

  const size_t o1 = (size_t)Btot * D_HX;
  #pragma unroll
  for (int m = 0; m < 2; ++m){
    #pragma unroll
    for (int t = 0; t < 2; ++t){
      #pragma unroll
      for (int r = 0; r < 4; ++r){
        const int row  = rowbase + m * 16 + lg * 4 + r;   // C/D: row=(l>>4)*4+reg
        const int hcol = hbase + t * 16 + l15;            //       col=l&15
        const size_t idx = (size_t)row * D_HX + hcol;
        float gi = acc[m][0][t][r] + bb[0][t];
        float gf = acc[m][1][t][r] + bb[1][t];
        float gc = acc[m][2][t][r] + bb[2][t];
        float go = acc[m][3][t][r] + bb[3][t];
        float it = fsigmoid(gi);
        float ft = fsigmoid(gf);
        float gt = ftanhf(gc);
        float ot = fsigmoid(go);
        float cn = ft * cin[idx] + it * gt;
        float hn = ot * ftanhf(cn);
        out[idx]          = hn;
        out[o1 + idx]     = hn;
        out[2 * o1 + idx] = cn;
      }
    }
  }
}

extern "C" void kernel_launch(void* const* d_in, const int* in_sizes, int n_in,
                              void* d_out, int out_size, void* d_ws, size_t ws_size,
                              hipStream_t stream){
  const float* x  = (const float*)d_in[0];
  const float* ht = (const float*)d_in[1];
  const float* ct = (const float*)d_in[2];
  unsigned short* Wt = (unsigned short*)d_ws;
  float* bcat = (float*)((char*)d_ws + (size_t)FOURH * KTOT * sizeof(unsigned short));
  const int Btot = in_sizes[0] / D_INX;

  prep_weights<<<FOURH, KTOT, 0, stream>>>(
      (const float*)d_in[3],  (const float*)d_in[4],  (const float*)d_in[5],
      (const float*)d_in[6],  (const float*)d_in[7],  (const float*)d_in[8],
      (const float*)d_in[9],  (const float*)d_in[10], (const float*)d_in[11],
      (const float*)d_in[12], (const float*)d_in[13], (const float*)d_in[14],
      Wt, bcat);

  lstm_fused<<<Btot / 64, 512, 0, stream>>>(x, ht, ct, Wt, bcat, (float*)d_out, Btot);
}

// Round 3
// 319.325 us; speedup vs baseline: 1.5755x; 1.5755x over previous
//
#include <hip/hip_runtime.h>

#define DH 128   // D_IN == D_H == 128

typedef __attribute__((ext_vector_type(8))) short bf16x8;
typedef __attribute__((ext_vector_type(8))) unsigned short u16x8;
typedef __attribute__((ext_vector_type(4))) float f32x4;
typedef __attribute__((ext_vector_type(4))) int   i32x4;

__device__ inline unsigned rnd_bf16(float f){
  unsigned u = __builtin_bit_cast(unsigned, f);
  u += 0x7fffu + ((u >> 16) & 1u);   // RNE
  return u;
}
__device__ inline int pk2(float a, float b){
  unsigned ua = rnd_bf16(a), ub = rnd_bf16(b);
  return (int)((ua >> 16) | (ub & 0xffff0000u));
}
__device__ inline float fsigmoid(float v){
  float e = __builtin_amdgcn_exp2f(v * -1.442695040888963f);
  return __builtin_amdgcn_rcpf(1.0f + e);
}
__device__ inline float ftanhf(float v){
  float e = __builtin_amdgcn_exp2f(v * 2.885390081777927f); // e^{2v}
  return 1.0f - 2.0f * __builtin_amdgcn_rcpf(1.0f + e);
}
__device__ inline void gload_lds16(const float* g, float* l){
  __builtin_amdgcn_global_load_lds(
      (const __attribute__((address_space(1))) void*)g,
      (__attribute__((address_space(3))) void*)l, 16, 0, 0);
}

// Wf[hs][g][t][ks][lane] : 16B bf16 fragment chunks in the exact per-wave read
// order -> each weight load is base + lane*16 (one contiguous 1KiB request).
// Lane (l15,lg) chunk = Wcat[ncol = g*128+hs*32+t*16+l15][k = ks*32+lg*8 .. +8]
__global__ void prep_weights(const float* __restrict__ Wxi, const float* __restrict__ Whi, const float* __restrict__ bi,
                             const float* __restrict__ Wxf, const float* __restrict__ Whf, const float* __restrict__ bf_,
                             const float* __restrict__ Wxc, const float* __restrict__ Whc, const float* __restrict__ bc,
                             const float* __restrict__ Wxo, const float* __restrict__ Who, const float* __restrict__ bo,
                             u16x8* __restrict__ Wf, float* __restrict__ bcat){
  int gid = blockIdx.x * 256 + threadIdx.x;   // 0..16383
  int lane = gid & 63;
  int ks   = (gid >> 6) & 7;
  int t    = (gid >> 9) & 1;
  int g    = (gid >> 10) & 3;
  int hsv  = (gid >> 12) & 3;
  int l15 = lane & 15, lg = lane >> 4;
  int hcol = hsv * 32 + t * 16 + l15;
  int kb   = ks * 32 + lg * 8;
  const float* Wx = (g == 0) ? Wxi : (g == 1) ? Wxf : (g == 2) ? Wxc : Wxo;
  const float* Wh = (g == 0) ? Whi : (g == 1) ? Whf : (g == 2) ? Whc : Who;
  u16x8 o;
  #pragma unroll
  for (int j = 0; j < 8; ++j){
    int k = kb + j;
    float v = (k < 128) ? Wx[k * DH + hcol] : Wh[(k - 128) * DH + hcol];
    o[j] = (unsigned short)(rnd_bf16(v) >> 16);
  }
  Wf[gid] = o;
  if (gid < 512){
    int gg = gid >> 7, hc = gid & 127;
    const float* bp = (gg == 0) ? bi : (gg == 1) ? bf_ : (gg == 2) ? bc : bo;
    bcat[gid] = bp[hc];
  }
}

// Block: 512 thr = 8 waves. Waves 0-3: rows [0,32); waves 4-7: rows [32,64).
// Wave (wid&3) owns h-cols [(wid&3)*32,+32) for ALL 4 gates -> elementwise lane-local.
// x/h staged in LDS (global_load_lds, XOR-swizzled both sides per rule 21).
__global__ __launch_bounds__(512, 4)
void lstm_fused(const float* __restrict__ x, const float* __restrict__ hin,
                const float* __restrict__ cin, const bf16x8* __restrict__ Wf,
                const float* __restrict__ bcat, float* __restrict__ out, int Btot){
  __shared__ __attribute__((aligned(16))) float xs [64 * DH];
  __shared__ __attribute__((aligned(16))) float hsb[64 * DH];

  const int tid  = threadIdx.x;
  const int l    = tid & 63;
  const int wid  = tid >> 6;       // 0..7
  const int mgrp = wid >> 2;       // 0/1
  const int hs   = wid & 3;        // h-slice
  const int rowblk  = blockIdx.x * 64;
  const int rowbase = rowblk + mgrp * 32;
  const int hbase   = hs * 32;
  const int l15  = l & 15;
  const int lg   = l >> 4;         // 0..3

  // ---- stage x,h -> LDS. chunk = 1024B = 2 rows of 512B; lane l -> dst+16*l.
  // LDS[row][cf] holds x[row][cf ^ ((row&7)<<2)] (float-index swizzle).
  #pragma unroll
  for (int i = 0; i < 4; ++i){
    int chunk = wid * 4 + i;                         // 0..31
    int row   = chunk * 2 + (l >> 5);                // 0..63
    int colf  = ((l & 31) * 4) ^ ((row & 7) << 2);   // swizzled source col
    const float* gx = x   + (size_t)(rowblk + row) * DH + colf;
    const float* gh = hin + (size_t)(rowblk + row) * DH + colf;
    gload_lds16(gx, &xs [chunk * 256]);
    gload_lds16(gh, &hsb[chunk * 256]);
  }
  __syncthreads();

  f32x4 acc[2][4][2];
  #pragma unroll
  for (int m = 0; m < 2; ++m)
    #pragma unroll
    for (int g = 0; g < 4; ++g)
      #pragma unroll
      for (int t = 0; t < 2; ++t)
        acc[m][g][t] = (f32x4){0.f, 0.f, 0.f, 0.f};

  const bf16x8* wv = Wf + (size_t)hs * 4096 + l;   // wave's fragment stream

  #pragma unroll
  for (int ks = 0; ks < 8; ++ks){
    const float* sb = (ks < 4) ? xs : hsb;
    bf16x8 a[2];
    #pragma unroll
    for (int m = 0; m < 2; ++m){
      const int row = mgrp * 32 + m * 16 + l15;      // LDS tile row
      const int sw  = (row & 7) << 2;
      const int c0  = (ks & 3) * 32 + lg * 8;
      const float4 f0 = *(const float4*)&sb[row * DH + ( c0      ^ sw)];
      const float4 f1 = *(const float4*)&sb[row * DH + ((c0 + 4) ^ sw)];
      i32x4 pk;
      pk[0] = pk2(f0.x, f0.y); pk[1] = pk2(f0.z, f0.w);
      pk[2] = pk2(f1.x, f1.y); pk[3] = pk2(f1.z, f1.w);
      a[m] = __builtin_bit_cast(bf16x8, pk);
    }
    #pragma unroll
    for (int g = 0; g < 4; ++g){
      #pragma unroll
      for (int t = 0; t < 2; ++t){
        bf16x8 bw = wv[(((g * 2 + t) * 8) + ks) * 64];
        acc[0][g][t] = __builtin_amdgcn_mfma_f32_16x16x32_bf16(a[0], bw, acc[0][g][t], 0, 0, 0);
        acc[1][g][t] = __builtin_amdgcn_mfma_f32_16x16x32_bf16(a[1], bw, acc[1][g][t], 0, 0, 0);
      }
    }
  }

  float bb[4][2];
  #pragma unroll
  for (int g = 0; g < 4; ++g)
    #pragma unroll
    for (int t = 0; t < 2; ++t)
      bb[g][t] = bcat[g * 128 + hbase + t * 16 + l15];

  const size_t o1 = (size_t)Btot * DH;
  #pragma unroll
  for (int m = 0; m < 2; ++m){
    #pragma unroll
    for (int t = 0; t < 2; ++t){
      #pragma unroll
      for (int r = 0; r < 4; ++r){
        const int row  = rowbase + m * 16 + lg * 4 + r;   // C/D: row=(l>>4)*4+reg
        const int hcol = hbase + t * 16 + l15;            //       col=l&15
        const size_t idx = (size_t)row * DH + hcol;
        float gi = acc[m][0][t][r] + bb[0][t];
        float gf = acc[m][1][t][r] + bb[1][t];
        float gc = acc[m][2][t][r] + bb[2][t];
        float go = acc[m][3][t][r] + bb[3][t];
        float it = fsigmoid(gi);
        float ft = fsigmoid(gf);
        float gt = ftanhf(gc);
        float ot = fsigmoid(go);
        float cn = ft * cin[idx] + it * gt;
        float hn = ot * ftanhf(cn);
        out[idx]          = hn;
        out[o1 + idx]     = hn;
        out[2 * o1 + idx] = cn;
      }
    }
  }
}

extern "C" void kernel_launch(void* const* d_in, const int* in_sizes, int n_in,
                              void* d_out, int out_size, void* d_ws, size_t ws_size,
                              hipStream_t stream){
  const float* x  = (const float*)d_in[0];
  const float* ht = (const float*)d_in[1];
  const float* ct = (const float*)d_in[2];
  u16x8* Wf   = (u16x8*)d_ws;                               // 16384 * 16B = 256KB
  float* bcat = (float*)((char*)d_ws + 16384 * 16);         // +2KB
  const int Btot = in_sizes[0] / DH;

  prep_weights<<<64, 256, 0, stream>>>(
      (const float*)d_in[3],  (const float*)d_in[4],  (const float*)d_in[5],
      (const float*)d_in[6],  (const float*)d_in[7],  (const float*)d_in[8],
      (const float*)d_in[9],  (const float*)d_in[10], (const float*)d_in[11],
      (const float*)d_in[12], (const float*)d_in[13], (const float*)d_in[14],
      Wf, bcat);

  lstm_fused<<<Btot / 64, 512, 0, stream>>>(x, ht, ct, (const bf16x8*)Wf, bcat,
                                            (float*)d_out, Btot);
}